// Round 13
// baseline (33533.972 us; speedup 1.0000x reference)
//
#include <hip/hip_runtime.h>

#define TT    8192
#define HD    1024
#define NBLK  256
#define NTHR  256
#define NBUF  4         // slot ring; generation tag distinguishes reuses

typedef int i32x4 __attribute__((ext_vector_type(4)));

// ---- LLC-coherent accesses (sc0 sc1 = coherent at the fabric/MALL) ----
__device__ __forceinline__ i32x4 llc_load4i(const int* p) {
  i32x4 r;
  asm volatile("global_load_dwordx4 %0, %1, off sc0 sc1\n\ts_waitcnt vmcnt(0)"
               : "=v"(r) : "v"(p) : "memory");
  return r;
}
__device__ __forceinline__ void llc_store1u(unsigned* p, unsigned v) {
  asm volatile("global_store_dword %0, %1, off sc0 sc1"
               :: "v"(p), "v"(v) : "memory");
}

__device__ __forceinline__ float sigf(float z) {
  return 1.0f / (1.0f + __expf(-z));
}
__device__ __forceinline__ float tanh_fast(float z) {
  float az = fabsf(z);
  float e  = __expf(2.0f * az);          // >= 1
  float t  = 1.0f - 2.0f / (e + 1.0f);
  return z < 0.0f ? -t : t;
}

#define FMA4(acc, hvv, wvv)                                      \
  acc = fmaf((hvv).x, (wvv).x, acc);                             \
  acc = fmaf((hvv).y, (wvv).y, acc);                             \
  acc = fmaf((hvv).z, (wvv).z, acc);                             \
  acc = fmaf((hvv).w, (wvv).w, acc);

// vbuf: u32[NBUF][HD].  h of step t -> slot t%4, encoded as
//   (float_bits & ~3) | gen,  gen = (t>>2)&3.
// Value and tag share ONE dword: a single dwordx4 poll per thread covers 4
// units, torn reads are impossible, and no sequencer/flag/drain exists —
// one fabric hop per step.  Writes to a slot carry gens ...g-1, g, g+1...
// (+1 mod 4 each reuse), so "gen == expected" uniquely identifies step t's
// write.  0xAA poison has gen 2; the first write to any slot has gen 0.
//
// RING SAFETY (NBUF=4): block P stores h_{t+4} (slot t%4, gen g+1) only
// after its poll for step t+3 succeeded, i.e. every block produced h_{t+3},
// hence every block's poll for t+2 succeeded, ... hence EVERY block's poll
// for step t (reading gen g of slot t%4, value+tag in one load) completed.
// No consumer can still be waiting on gen g when gen g+1 lands.  QED.
//
// NUMERICS: clearing 2 mantissa bits perturbs each h by <= 2^-22 rel
// (<1.8e-7 abs); all blocks decode identically, so the recurrence stays
// bit-deterministic chip-wide.
extern "C" __global__ __launch_bounds__(NTHR, 1)
void lstm_persistent(const float* __restrict__ x,
                     const float* __restrict__ W_ih,
                     const float* __restrict__ W_hh,
                     const float* __restrict__ b_ih,
                     const float* __restrict__ b_hh,
                     const float* __restrict__ W_fc,
                     const float* __restrict__ b_fc,
                     float* __restrict__ out,
                     unsigned* __restrict__ vbuf)
{
  __shared__ float x_lds[TT];     // 32 KB: whole input sequence
  __shared__ float h_lds[HD];     //  4 KB: broadcast of h_{t-1}

  const int tid  = threadIdx.x;
  const int wave = tid >> 6;
  const int lane = tid & 63;
  const int g    = lane >> 4;     // gate 0..3 (i,f,g,o)
  const int kc   = lane & 15;     // k-chunk within the 1024-dot
  const int blk  = blockIdx.x;
  const int unit = blk * 4 + wave;

  // ---- one-time staging -------------------------------------------------
  for (int i = tid; i < TT / 4; i += NTHR)
    ((float4*)x_lds)[i] = ((const float4*)x)[i];

  // W_hh row (gate g, unit) — lane covers k = m*64 + kc*4 + {0..3}
  float4 w4[16];
  {
    const float* wr = W_hh + (size_t)(g * HD + unit) * HD + kc * 4;
#pragma unroll
    for (int m = 0; m < 16; ++m)
      w4[m] = *((const float4*)(wr + m * 64));
  }
  float4 wfc4[4];
#pragma unroll
  for (int m = 0; m < 4; ++m)
    wfc4[m] = *((const float4*)(W_fc + m * 256 + lane * 4));
  const float bfc_val = b_fc[0];

  float wih_g[4], bs_g[4];
#pragma unroll
  for (int q = 0; q < 4; ++q) {
    int r = q * HD + unit;
    wih_g[q] = W_ih[r];
    bs_g[q]  = b_ih[r] + b_hh[r];
  }
  float c_state = 0.0f;
  __syncthreads();                // x_lds ready

  // ---- the sequential scan: ONE fabric hop per step ---------------------
  for (int t = 0; t < TT; ++t) {
    const bool doproj = (t > 0) && (wave == 1) && (blk == (t & 255));
    float accs = 0.0f;
    float4 hp4[4];

    if (t > 0) {
      const int slot = (t - 1) & (NBUF - 1);
      const int gexp = ((t - 1) >> 2) & 3;     // expected generation
      // direct poll: ONE dwordx4 per thread (its 4 units, value+tag fused)
      const int* src = (const int*)(vbuf + (size_t)slot * HD + tid * 4);
      i32x4 V;
      do {
        V = llc_load4i(src);
      } while ((((V.x ^ gexp) | (V.y ^ gexp) | (V.z ^ gexp) | (V.w ^ gexp)) & 3) != 0);
      float4 hv;
      hv.x = __int_as_float(V.x & ~3);
      hv.y = __int_as_float(V.y & ~3);
      hv.z = __int_as_float(V.z & ~3);
      hv.w = __int_as_float(V.w & ~3);
      ((float4*)h_lds)[tid] = hv;
      __syncthreads();

      // fragments + 64 FMAs (4 independent sub-chains)
      const float* hp = h_lds + kc * 4;
      float s0 = 0.f, s1 = 0.f, s2 = 0.f, s3 = 0.f;
#pragma unroll
      for (int mb = 0; mb < 4; ++mb) {
        float4 ha = *((const float4*)(hp + (mb * 4 + 0) * 64));
        float4 hb = *((const float4*)(hp + (mb * 4 + 1) * 64));
        float4 hc = *((const float4*)(hp + (mb * 4 + 2) * 64));
        float4 hd = *((const float4*)(hp + (mb * 4 + 3) * 64));
        FMA4(s0, ha, w4[mb * 4 + 0]);
        FMA4(s1, hb, w4[mb * 4 + 1]);
        FMA4(s2, hc, w4[mb * 4 + 2]);
        FMA4(s3, hd, w4[mb * 4 + 3]);
      }
      accs = (s0 + s1) + (s2 + s3);

      if (doproj) {
#pragma unroll
        for (int m = 0; m < 4; ++m)
          hp4[m] = *((const float4*)(h_lds + m * 256 + lane * 4));
      }
    }

    // 4-round butterfly over kc: every lane in a gate-group gets the row sum
#pragma unroll
    for (int s = 1; s < 16; s <<= 1)
      accs += __shfl_xor(accs, s);

    float gi = __shfl(accs, 0);
    float gf = __shfl(accs, 16);
    float gg = __shfl(accs, 32);
    float go = __shfl(accs, 48);

    if (lane == 0) {
      float xt = x_lds[t];
      gi += fmaf(xt, wih_g[0], bs_g[0]);
      gf += fmaf(xt, wih_g[1], bs_g[1]);
      gg += fmaf(xt, wih_g[2], bs_g[2]);
      go += fmaf(xt, wih_g[3], bs_g[3]);
      c_state  = sigf(gf) * c_state + sigf(gi) * tanh_fast(gg);
      float hn = sigf(go) * tanh_fast(c_state);
      // encode: low 2 bits = generation tag; single 4-B fire & forget
      unsigned enc = (__float_as_uint(hn) & ~3u) | (unsigned)((t >> 2) & 3);
      llc_store1u(vbuf + (size_t)(t & (NBUF - 1)) * HD + unit, enc);
    }

    // fused output projection for step t-1 (register-only, off crit path)
    if (doproj) {
      float p = 0.f;
#pragma unroll
      for (int m = 0; m < 4; ++m) { FMA4(p, hp4[m], wfc4[m]); }
#pragma unroll
      for (int s = 1; s < 64; s <<= 1) p += __shfl_xor(p, s);
      if (lane == 0) out[t - 1] = p + bfc_val;
    }
  }

  // ---- epilogue: out[TT-1] by block 0 -----------------------------------
  if (blk == 0) {
    const int slot = (TT - 1) & (NBUF - 1);
    const int gexp = ((TT - 1) >> 2) & 3;
    const int* src = (const int*)(vbuf + (size_t)slot * HD + tid * 4);
    i32x4 V;
    do {
      V = llc_load4i(src);
    } while ((((V.x ^ gexp) | (V.y ^ gexp) | (V.z ^ gexp) | (V.w ^ gexp)) & 3) != 0);
    float4 hv;
    hv.x = __int_as_float(V.x & ~3);
    hv.y = __int_as_float(V.y & ~3);
    hv.z = __int_as_float(V.z & ~3);
    hv.w = __int_as_float(V.w & ~3);
    ((float4*)h_lds)[tid] = hv;
    __syncthreads();
    if (wave == 1) {
      float p = 0.f;
#pragma unroll
      for (int m = 0; m < 4; ++m) {
        float4 hm = *((const float4*)(h_lds + m * 256 + lane * 4));
        FMA4(p, hm, wfc4[m]);
      }
#pragma unroll
      for (int s = 1; s < 64; s <<= 1) p += __shfl_xor(p, s);
      if (lane == 0) out[TT - 1] = p + bfc_val;
    }
  }
}

extern "C" void kernel_launch(void* const* d_in, const int* in_sizes, int n_in,
                              void* d_out, int out_size, void* d_ws, size_t ws_size,
                              hipStream_t stream) {
  const float* x   = (const float*)d_in[0];
  const float* Wih = (const float*)d_in[1];
  const float* Whh = (const float*)d_in[2];
  const float* bih = (const float*)d_in[3];
  const float* bhh = (const float*)d_in[4];
  const float* Wfc = (const float*)d_in[5];
  const float* bfc = (const float*)d_in[6];
  float* out = (float*)d_out;

  // ws: vbuf u32[NBUF][HD] = 16 KB.  0xAA fill (gen bits = 2) can never
  // alias the first generation (gen 0); memset guards the first,
  // un-poisoned call.
  unsigned* vbuf = (unsigned*)d_ws;
  hipMemsetAsync(d_ws, 0xAA, (size_t)NBUF * HD * sizeof(unsigned), stream);
  hipLaunchKernelGGL(lstm_persistent, dim3(NBLK), dim3(NTHR), 0, stream,
                     x, Wih, Whh, bih, bhh, Wfc, bfc, out, vbuf);
}